// Round 3
// baseline (2514.776 us; speedup 1.0000x reference)
//
#include <hip/hip_runtime.h>

#define NPN   1024            // nodes per slice
#define NB    512             // batch (slices)
#define NE_S  2048            // edges per slice
#define DD    128             // feature dim
#define NN    (NB * NPN)      // 524288 total nodes
#define NE    (NB * NE_S)     // 1048576 total edges

typedef short s16x8 __attribute__((ext_vector_type(8)));
typedef float f32x4 __attribute__((ext_vector_type(4)));

static __device__ __forceinline__ unsigned short f2bf(float f) {
    unsigned u = __builtin_bit_cast(unsigned, f);
    unsigned r = (u + 0x7FFFu + ((u >> 16) & 1u)) >> 16;   // RNE
    return (unsigned short)r;
}
static __device__ __forceinline__ float bf2f(unsigned short h) {
    unsigned u = ((unsigned)h) << 16;
    return __builtin_bit_cast(float, u);
}

// ---------- CSR / degree precompute (layer-invariant) ----------

__global__ void k_count(const int* __restrict__ ei, int* __restrict__ deg) {
    int t = blockIdx.x * 256 + threadIdx.x;          // 0..NE-1
    int b = t >> 11, e = t & (NE_S - 1);
    int col = ei[b * (2 * NE_S) + NE_S + e];
    atomicAdd(&deg[b * NPN + col], 1);
}

__global__ void k_dinv(const int* __restrict__ deg, float* __restrict__ dinv) {
    int i = blockIdx.x * 256 + threadIdx.x;
    dinv[i] = rsqrtf((float)(deg[i] + 1));           // +1 self-loop
}

__global__ __launch_bounds__(1024) void k_scan(const int* __restrict__ deg,
                                               int* __restrict__ coff,
                                               int* __restrict__ cur) {
    __shared__ int s[NPN];
    int b = blockIdx.x, t = threadIdx.x;
    int v = deg[b * NPN + t];
    s[t] = v;
    __syncthreads();
    for (int off = 1; off < NPN; off <<= 1) {
        int add = (t >= off) ? s[t - off] : 0;
        __syncthreads();
        s[t] += add;
        __syncthreads();
    }
    coff[b * NPN + t] = b * NE_S + (s[t] - v);       // exclusive prefix, global offset
    cur[b * NPN + t] = 0;
}

__global__ void k_fill(const int* __restrict__ ei, const float* __restrict__ dinv,
                       const int* __restrict__ coff, int* __restrict__ cur,
                       int2* __restrict__ csd, float* __restrict__ cnorm) {
    int t = blockIdx.x * 256 + threadIdx.x;
    int b = t >> 11, e = t & (NE_S - 1);
    int r = ei[b * (2 * NE_S) + e];
    int c = ei[b * (2 * NE_S) + NE_S + e];
    int gr = b * NPN + r, gc = b * NPN + c;
    int pos = coff[gc] + atomicAdd(&cur[gc], 1);
    csd[pos]   = make_int2(gr, gc);
    cnorm[pos] = dinv[gr] * dinv[gc];
}

// ---------- W pre-transpose + bf16 hi/lo split (per layer, tiny) ----------

__global__ __launch_bounds__(256) void k_wsplit(const float* __restrict__ W,
                                                short* __restrict__ WTh,
                                                short* __restrict__ WTl) {
    int idx = blockIdx.x * 256 + threadIdx.x;        // 0..16383
    int k = idx >> 7, n = idx & 127;
    float f = W[idx];
    unsigned short h = f2bf(f);
    unsigned short l = f2bf(f - bf2f(h));
    WTh[n * DD + k] = (short)h;
    WTl[n * DD + k] = (short)l;
}

// ---------- fused GCN layer: out = relu((A_hat x) @ W + b) ----------
// 512 thr / 8 waves / block; 128x128 output tile; LDS = one 64 KiB union:
//   phase A: fp32 accumulator sAcc[128][128], de-interleaved cols
//            (feature 2c -> col c, feature 2c+1 -> col 64+c): every
//            init write / edge ds_add_f32 / convert read is bank-perfect.
//   phase B: bf16 hi half [0,32K) + lo half [32K,64K), XOR-swizzled.
// Edge gather is FLAT: block's CSR range split evenly over 8 waves;
// metadata loaded lane-parallel, x-rows loaded 8-deep in flight,
// accumulated with LDS float atomics (safe across waves).

__global__ __launch_bounds__(512, 4) void k_layer(const float* __restrict__ x,
                                                  unsigned gmask,
                                                  const short* __restrict__ WTh,
                                                  const short* __restrict__ WTl,
                                                  const float* __restrict__ bias,
                                                  const float* __restrict__ dinv,
                                                  const int* __restrict__ coff,
                                                  const int2* __restrict__ csd,
                                                  const float* __restrict__ cnorm,
                                                  float* __restrict__ out) {
    __shared__ float sBuf[128 * DD];     // 64 KiB union
    float* sAcc = sBuf;
    char*  sH   = (char*)sBuf;           // after repack: hi bytes [0,32K)
    char*  sL   = (char*)sBuf + 32768;   // lo bytes [32K,64K)

    int t = threadIdx.x;
    int wave = t >> 6, lane = t & 63;
    // XCD-aware swizzle: 8 blocks/slice land on one XCD -> slice rows L2-hit
    int wb = (int)((blockIdx.x & 7) * 512 + (blockIdx.x >> 3));
    int m0 = wb * 128;

    int n  = lane & 15;
    int kq = lane >> 4;

    // ---- B fragments from global (L2-resident 64 KB, loaded once) ----
    const short* bhp = &WTh[(wave * 16 + n) * DD + kq * 8];
    const short* blp = &WTl[(wave * 16 + n) * DD + kq * 8];
    s16x8 bh[4], bl[4];
    #pragma unroll
    for (int ks = 0; ks < 4; ++ks) {
        bh[ks] = *(const s16x8*)(bhp + ks * 32);
        bl[ks] = *(const s16x8*)(blp + ks * 32);
    }

    // ---- self-loop init: rows wave*16..+15, lane covers features 2l,2l+1 ----
    #pragma unroll 2
    for (int h = 0; h < 2; ++h) {
        float2 sv[8]; float dvv[8];
        #pragma unroll
        for (int i = 0; i < 8; ++i) {
            int row = wave * 16 + h * 8 + i;
            int g = m0 + row;
            dvv[i] = dinv[g];
            sv[i] = *(const float2*)&x[(size_t)((unsigned)g & gmask) * DD + lane * 2];
        }
        #pragma unroll
        for (int i = 0; i < 8; ++i) {
            int row = wave * 16 + h * 8 + i;
            float s = dvv[i] * dvv[i];
            sAcc[row * DD + lane]      = s * sv[i].x;
            sAcc[row * DD + 64 + lane] = s * sv[i].y;
        }
    }
    __syncthreads();

    // ---- flat edge gather ----
    int cb0 = coff[m0];
    int cb1 = (m0 + 128 < NN) ? coff[m0 + 128] : NE;
    int Eb  = cb1 - cb0;
    int eBeg = cb0 + (Eb * wave) / 8;
    int eEnd = cb0 + (Eb * (wave + 1)) / 8;

    for (int c0 = eBeg; c0 < eEnd; c0 += 64) {
        int nC = min(64, eEnd - c0);
        int2 sd = make_int2(m0, m0); float nw = 0.f;
        if (lane < nC) { sd = csd[c0 + lane]; nw = cnorm[c0 + lane]; }
        for (int b0 = 0; b0 < nC; b0 += 8) {
            float2 v[8]; int dl[8]; float wj[8];
            int nB = min(8, nC - b0);
            #pragma unroll
            for (int j = 0; j < 8; ++j) {
                if (j < nB) {
                    int src = __shfl(sd.x, b0 + j);
                    dl[j]   = __shfl(sd.y, b0 + j) - m0;
                    wj[j]   = __shfl(nw,   b0 + j);
                    v[j] = *(const float2*)&x[(size_t)((unsigned)src & gmask) * DD + lane * 2];
                }
            }
            #pragma unroll
            for (int j = 0; j < 8; ++j) {
                if (j < nB) {
                    atomicAdd(&sAcc[dl[j] * DD + lane],      wj[j] * v[j].x);
                    atomicAdd(&sAcc[dl[j] * DD + 64 + lane], wj[j] * v[j].y);
                }
            }
        }
    }
    __syncthreads();

    // ---- in-place repack: fp32 -> bf16 hi/lo, XOR-swizzled ----
    float fe[16], fo[16];
    #pragma unroll
    for (int i = 0; i < 16; ++i) {
        int row = wave * 16 + i;
        fe[i] = sAcc[row * DD + lane];        // feature 2*lane
        fo[i] = sAcc[row * DD + 64 + lane];   // feature 2*lane+1
    }
    __syncthreads();
    #pragma unroll
    for (int i = 0; i < 16; ++i) {
        int row = wave * 16 + i;
        unsigned short hx = f2bf(fe[i]); unsigned short lx = f2bf(fe[i] - bf2f(hx));
        unsigned short hy = f2bf(fo[i]); unsigned short ly = f2bf(fo[i] - bf2f(hy));
        unsigned bo = ((unsigned)row * 256u + (unsigned)lane * 4u) ^ ((unsigned)(row & 7) << 4);
        *(unsigned*)(sH + bo) = ((unsigned)hy << 16) | hx;
        *(unsigned*)(sL + bo) = ((unsigned)ly << 16) | lx;
    }
    __syncthreads();

    // ---- MFMA phase: wave strip = rows 0..127, cols wave*16..+15 ----
    f32x4 acc[8];
    #pragma unroll
    for (int m = 0; m < 8; ++m) acc[m] = (f32x4){0.f, 0.f, 0.f, 0.f};

    #pragma unroll
    for (int ks = 0; ks < 4; ++ks) {
        #pragma unroll
        for (int m = 0; m < 8; ++m) {
            int row = m * 16 + n;
            unsigned bo = ((unsigned)row * 256u + (unsigned)(ks * 64 + kq * 16))
                          ^ ((unsigned)(row & 7) << 4);
            s16x8 ah = *(const s16x8*)(sH + bo);
            s16x8 al = *(const s16x8*)(sL + bo);
            acc[m] = __builtin_amdgcn_mfma_f32_16x16x32_bf16(ah, bh[ks], acc[m], 0, 0, 0);
            acc[m] = __builtin_amdgcn_mfma_f32_16x16x32_bf16(ah, bl[ks], acc[m], 0, 0, 0);
            acc[m] = __builtin_amdgcn_mfma_f32_16x16x32_bf16(al, bh[ks], acc[m], 0, 0, 0);
        }
    }

    // ---- epilogue: bias + relu; C/D layout col=lane&15, row=kq*4+reg ----
    int col = wave * 16 + n;
    float bv = bias[col];
    #pragma unroll
    for (int m = 0; m < 8; ++m) {
        #pragma unroll
        for (int r = 0; r < 4; ++r) {
            int row = m * 16 + kq * 4 + r;
            float vv = acc[m][r] + bv;
            out[(size_t)(m0 + row) * DD + col] = fmaxf(vv, 0.f);
        }
    }
}

// ---------- launch ----------

extern "C" void kernel_launch(void* const* d_in, const int* in_sizes, int n_in,
                              void* d_out, int out_size, void* d_ws, size_t ws_size,
                              hipStream_t stream) {
    const int*   ei  = (const int*)d_in[0];
    const float* emb = (const float*)d_in[1];
    const float* W1  = (const float*)d_in[2];
    const float* b1  = (const float*)d_in[3];
    const float* W2  = (const float*)d_in[4];
    const float* b2  = (const float*)d_in[5];
    const float* W3  = (const float*)d_in[6];
    const float* b3  = (const float*)d_in[7];
    float* out = (float*)d_out;

    float* x_mid = (float*)d_ws;                       // NN*DD floats (256 MiB)
    float* dinv  = x_mid + (size_t)NN * DD;
    int*   deg   = (int*)(dinv + NN);
    int*   coff  = deg + NN;
    int*   cur   = coff + NN;
    int2*  csd   = (int2*)(cur + NN);                  // NE int2 (8 MiB)
    float* cnorm = (float*)(csd + NE);
    short* WTh1  = (short*)(cnorm + NE);
    short* WTl1  = WTh1 + DD * DD;
    short* WTh2  = WTl1 + DD * DD;
    short* WTl2  = WTh2 + DD * DD;
    short* WTh3  = WTl2 + DD * DD;
    short* WTl3  = WTh3 + DD * DD;

    hipMemsetAsync(deg, 0, NN * sizeof(int), stream);
    k_count<<<NE / 256, 256, 0, stream>>>(ei, deg);
    k_dinv<<<NN / 256, 256, 0, stream>>>(deg, dinv);
    k_scan<<<NB, NPN, 0, stream>>>(deg, coff, cur);
    k_fill<<<NE / 256, 256, 0, stream>>>(ei, dinv, coff, cur, csd, cnorm);

    k_wsplit<<<64, 256, 0, stream>>>(W1, WTh1, WTl1);
    k_wsplit<<<64, 256, 0, stream>>>(W2, WTh2, WTl2);
    k_wsplit<<<64, 256, 0, stream>>>(W3, WTh3, WTl3);

    // layer 1: x = tiled emb (gmask folds node id onto the 1024-row table)
    k_layer<<<NN / 128, 512, 0, stream>>>(emb, NPN - 1, WTh1, WTl1, b1,
                                          dinv, coff, csd, cnorm, out);
    // layer 2: out -> x_mid
    k_layer<<<NN / 128, 512, 0, stream>>>(out, 0xFFFFFFFFu, WTh2, WTl2, b2,
                                          dinv, coff, csd, cnorm, x_mid);
    // layer 3: x_mid -> out
    k_layer<<<NN / 128, 512, 0, stream>>>(x_mid, 0xFFFFFFFFu, WTh3, WTl3, b3,
                                          dinv, coff, csd, cnorm, out);
}

// Round 4
// 1231.227 us; speedup vs baseline: 2.0425x; 2.0425x over previous
//
#include <hip/hip_runtime.h>

#define NPN   1024            // nodes per slice
#define NB    512             // batch (slices)
#define NE_S  2048            // edges per slice
#define DD    128             // feature dim
#define NN    (NB * NPN)      // 524288 total nodes
#define NE    (NB * NE_S)     // 1048576 total edges

typedef short s16x8 __attribute__((ext_vector_type(8)));
typedef float f32x4 __attribute__((ext_vector_type(4)));

static __device__ __forceinline__ unsigned short f2bf(float f) {
    unsigned u = __builtin_bit_cast(unsigned, f);
    unsigned r = (u + 0x7FFFu + ((u >> 16) & 1u)) >> 16;   // RNE
    return (unsigned short)r;
}
static __device__ __forceinline__ float bf2f(unsigned short h) {
    unsigned u = ((unsigned)h) << 16;
    return __builtin_bit_cast(float, u);
}

// ---------- CSR / degree precompute (layer-invariant) ----------

__global__ void k_count(const int* __restrict__ ei, int* __restrict__ deg) {
    int t = blockIdx.x * 256 + threadIdx.x;          // 0..NE-1
    int b = t >> 11, e = t & (NE_S - 1);
    int col = ei[b * (2 * NE_S) + NE_S + e];
    atomicAdd(&deg[b * NPN + col], 1);
}

__global__ void k_dinv(const int* __restrict__ deg, float* __restrict__ dinv) {
    int i = blockIdx.x * 256 + threadIdx.x;
    dinv[i] = rsqrtf((float)(deg[i] + 1));           // +1 self-loop
}

__global__ __launch_bounds__(1024) void k_scan(const int* __restrict__ deg,
                                               int* __restrict__ coff,
                                               int* __restrict__ cur) {
    __shared__ int s[NPN];
    int b = blockIdx.x, t = threadIdx.x;
    int v = deg[b * NPN + t];
    s[t] = v;
    __syncthreads();
    for (int off = 1; off < NPN; off <<= 1) {
        int add = (t >= off) ? s[t - off] : 0;
        __syncthreads();
        s[t] += add;
        __syncthreads();
    }
    coff[b * NPN + t] = b * NE_S + (s[t] - v);       // exclusive prefix, global offset
    cur[b * NPN + t] = 0;
}

// packed edge meta: .x = src_local | (dst_local<<16), .y = bitcast(norm)
__global__ void k_fill(const int* __restrict__ ei, const float* __restrict__ dinv,
                       const int* __restrict__ coff, int* __restrict__ cur,
                       int2* __restrict__ cmeta) {
    int t = blockIdx.x * 256 + threadIdx.x;
    int b = t >> 11, e = t & (NE_S - 1);
    int r = ei[b * (2 * NE_S) + e];
    int c = ei[b * (2 * NE_S) + NE_S + e];
    int gr = b * NPN + r, gc = b * NPN + c;
    int pos = coff[gc] + atomicAdd(&cur[gc], 1);
    float nw = dinv[gr] * dinv[gc];
    cmeta[pos] = make_int2(r | (c << 16), __builtin_bit_cast(int, nw));
}

// ---------- W pre-transpose + bf16 hi/lo split (per layer, tiny) ----------

__global__ __launch_bounds__(256) void k_wsplit(const float* __restrict__ W,
                                                short* __restrict__ WTh,
                                                short* __restrict__ WTl) {
    int idx = blockIdx.x * 256 + threadIdx.x;        // 0..16383
    int k = idx >> 7, n = idx & 127;
    float f = W[idx];
    unsigned short h = f2bf(f);
    unsigned short l = f2bf(f - bf2f(h));
    WTh[n * DD + k] = (short)h;
    WTl[n * DD + k] = (short)l;
}

// ---------- fused GCN layer: out = relu((A_hat x) @ W + b) ----------
// 512 thr / 8 waves / block; 128x128 output tile; 64 KiB LDS union:
//   phase A: fp32 accumulator sAcc[128][128], de-interleaved cols.
//   phase B: bf16 hi half [0,32K) + lo half [32K,64K), XOR-swizzled.
// Gather: wave w owns rows w*16..+15 and their contiguous CSR edge range.
// Edge meta broadcast via v_readlane (scalar path, no shfl/LDS in the
// address chain); 8 independent x-row loads in flight; run-based
// accumulation (edges dst-sorted) -> LDS add once per run, not per edge.

__global__ __launch_bounds__(512, 4) void k_layer(const float* __restrict__ x,
                                                  unsigned gmask,
                                                  const short* __restrict__ WTh,
                                                  const short* __restrict__ WTl,
                                                  const float* __restrict__ bias,
                                                  const float* __restrict__ dinv,
                                                  const int* __restrict__ coff,
                                                  const int2* __restrict__ cmeta,
                                                  float* __restrict__ out) {
    __shared__ float sBuf[128 * DD];     // 64 KiB union
    float* sAcc = sBuf;
    char*  sH   = (char*)sBuf;           // after repack: hi bytes [0,32K)
    char*  sL   = (char*)sBuf + 32768;   // lo bytes [32K,64K)

    int t = threadIdx.x;
    int wave = t >> 6, lane = t & 63;
    // XCD-aware swizzle: 8 blocks/slice land on one XCD -> slice rows L2-hit
    int wb = (int)((blockIdx.x & 7) * 512 + (blockIdx.x >> 3));
    int m0 = wb * 128;
    int sbase = (wb >> 3) << 10;         // slice base node

    int n  = lane & 15;
    int kq = lane >> 4;

    // wave's CSR range (scalarized -> uniform control flow)
    int r0g = m0 + wave * 16;
    int eBeg = __builtin_amdgcn_readfirstlane(coff[r0g]);
    int eEnd = __builtin_amdgcn_readfirstlane((r0g + 16 < NN) ? coff[r0g + 16] : NE);

    // ---- B fragments from global (L2-resident 64 KB, loaded once) ----
    const short* bhp = &WTh[(wave * 16 + n) * DD + kq * 8];
    const short* blp = &WTl[(wave * 16 + n) * DD + kq * 8];
    s16x8 bh[4], bl[4];
    #pragma unroll
    for (int ks = 0; ks < 4; ++ks) {
        bh[ks] = *(const s16x8*)(bhp + ks * 32);
        bl[ks] = *(const s16x8*)(blp + ks * 32);
    }

    // ---- self-loop init: rows wave*16..+15, lane covers features 2l,2l+1 ----
    #pragma unroll 2
    for (int h = 0; h < 2; ++h) {
        float2 sv[8]; float dvv[8];
        #pragma unroll
        for (int i = 0; i < 8; ++i) {
            int row = wave * 16 + h * 8 + i;
            int g = m0 + row;
            dvv[i] = dinv[g];
            sv[i] = *(const float2*)&x[(size_t)((unsigned)g & gmask) * DD + lane * 2];
        }
        #pragma unroll
        for (int i = 0; i < 8; ++i) {
            int row = wave * 16 + h * 8 + i;
            float s = dvv[i] * dvv[i];
            sAcc[row * DD + lane]      = s * sv[i].x;
            sAcc[row * DD + 64 + lane] = s * sv[i].y;
        }
    }
    // no barrier needed: this wave only touches its own 16 rows below

    // ---- edge walk: run-based accumulation, 8 loads in flight ----
    float ax = 0.f, ay = 0.f;
    int curRow = -1;
    for (int c0 = eBeg; c0 < eEnd; c0 += 64) {
        int nC = eEnd - c0; nC = nC > 64 ? 64 : nC;
        // pad lanes: src10=0 (valid row, w=0), dst10=0xFFFF (run-breaker)
        int2 md = make_int2((int)0xFFFF0000u, 0);
        if (lane < nC) md = cmeta[c0 + lane];
        int nB = (nC + 7) & ~7;
        for (int b0 = 0; b0 < nB; b0 += 8) {
            float2 v[8]; int pj[8];
            #pragma unroll
            for (int j = 0; j < 8; ++j) {
                pj[j] = __builtin_amdgcn_readlane(md.x, b0 + j);
                int src = sbase + (pj[j] & 0xFFFF);
                v[j] = *(const float2*)&x[(size_t)((unsigned)src & gmask) * DD + lane * 2];
            }
            #pragma unroll
            for (int j = 0; j < 8; ++j) {
                int dst = sbase + (int)(((unsigned)pj[j]) >> 16);
                float w = __builtin_bit_cast(float, __builtin_amdgcn_readlane(md.y, b0 + j));
                if (dst != curRow) {
                    unsigned rl = (unsigned)(curRow - m0);
                    if (rl < 128u) {
                        atomicAdd(&sAcc[rl * DD + lane],      ax);
                        atomicAdd(&sAcc[rl * DD + 64 + lane], ay);
                    }
                    curRow = dst; ax = 0.f; ay = 0.f;
                }
                ax = fmaf(w, v[j].x, ax);
                ay = fmaf(w, v[j].y, ay);
            }
        }
    }
    {
        unsigned rl = (unsigned)(curRow - m0);
        if (rl < 128u) {
            atomicAdd(&sAcc[rl * DD + lane],      ax);
            atomicAdd(&sAcc[rl * DD + 64 + lane], ay);
        }
    }
    __syncthreads();

    // ---- in-place repack: fp32 -> bf16 hi/lo, XOR-swizzled ----
    float fe[16], fo[16];
    #pragma unroll
    for (int i = 0; i < 16; ++i) {
        int row = wave * 16 + i;
        fe[i] = sAcc[row * DD + lane];        // feature 2*lane
        fo[i] = sAcc[row * DD + 64 + lane];   // feature 2*lane+1
    }
    __syncthreads();
    #pragma unroll
    for (int i = 0; i < 16; ++i) {
        int row = wave * 16 + i;
        unsigned short hx = f2bf(fe[i]); unsigned short lx = f2bf(fe[i] - bf2f(hx));
        unsigned short hy = f2bf(fo[i]); unsigned short ly = f2bf(fo[i] - bf2f(hy));
        unsigned bo = ((unsigned)row * 256u + (unsigned)lane * 4u) ^ ((unsigned)(row & 7) << 4);
        *(unsigned*)(sH + bo) = ((unsigned)hy << 16) | hx;
        *(unsigned*)(sL + bo) = ((unsigned)ly << 16) | lx;
    }
    __syncthreads();

    // ---- MFMA phase: wave strip = rows 0..127, cols wave*16..+15 ----
    f32x4 acc[8];
    #pragma unroll
    for (int m = 0; m < 8; ++m) acc[m] = (f32x4){0.f, 0.f, 0.f, 0.f};

    #pragma unroll
    for (int ks = 0; ks < 4; ++ks) {
        #pragma unroll
        for (int m = 0; m < 8; ++m) {
            int row = m * 16 + n;
            unsigned bo = ((unsigned)row * 256u + (unsigned)(ks * 64 + kq * 16))
                          ^ ((unsigned)(row & 7) << 4);
            s16x8 ah = *(const s16x8*)(sH + bo);
            s16x8 al = *(const s16x8*)(sL + bo);
            acc[m] = __builtin_amdgcn_mfma_f32_16x16x32_bf16(ah, bh[ks], acc[m], 0, 0, 0);
            acc[m] = __builtin_amdgcn_mfma_f32_16x16x32_bf16(ah, bl[ks], acc[m], 0, 0, 0);
            acc[m] = __builtin_amdgcn_mfma_f32_16x16x32_bf16(al, bh[ks], acc[m], 0, 0, 0);
        }
    }

    // ---- epilogue: bias + relu; C/D layout col=lane&15, row=kq*4+reg ----
    int col = wave * 16 + n;
    float bv = bias[col];
    #pragma unroll
    for (int m = 0; m < 8; ++m) {
        #pragma unroll
        for (int r = 0; r < 4; ++r) {
            int row = m * 16 + kq * 4 + r;
            float vv = acc[m][r] + bv;
            out[(size_t)(m0 + row) * DD + col] = fmaxf(vv, 0.f);
        }
    }
}

// ---------- launch ----------

extern "C" void kernel_launch(void* const* d_in, const int* in_sizes, int n_in,
                              void* d_out, int out_size, void* d_ws, size_t ws_size,
                              hipStream_t stream) {
    const int*   ei  = (const int*)d_in[0];
    const float* emb = (const float*)d_in[1];
    const float* W1  = (const float*)d_in[2];
    const float* b1  = (const float*)d_in[3];
    const float* W2  = (const float*)d_in[4];
    const float* b2  = (const float*)d_in[5];
    const float* W3  = (const float*)d_in[6];
    const float* b3  = (const float*)d_in[7];
    float* out = (float*)d_out;

    float* x_mid = (float*)d_ws;                       // NN*DD floats (256 MiB)
    float* dinv  = x_mid + (size_t)NN * DD;
    int*   deg   = (int*)(dinv + NN);
    int*   coff  = deg + NN;
    int*   cur   = coff + NN;
    int2*  cmeta = (int2*)(cur + NN);                  // NE int2 (8 MiB)
    short* WTh1  = (short*)(cmeta + NE);
    short* WTl1  = WTh1 + DD * DD;
    short* WTh2  = WTl1 + DD * DD;
    short* WTl2  = WTh2 + DD * DD;
    short* WTh3  = WTl2 + DD * DD;
    short* WTl3  = WTh3 + DD * DD;

    hipMemsetAsync(deg, 0, NN * sizeof(int), stream);
    k_count<<<NE / 256, 256, 0, stream>>>(ei, deg);
    k_dinv<<<NN / 256, 256, 0, stream>>>(deg, dinv);
    k_scan<<<NB, NPN, 0, stream>>>(deg, coff, cur);
    k_fill<<<NE / 256, 256, 0, stream>>>(ei, dinv, coff, cur, cmeta);

    k_wsplit<<<64, 256, 0, stream>>>(W1, WTh1, WTl1);
    k_wsplit<<<64, 256, 0, stream>>>(W2, WTh2, WTl2);
    k_wsplit<<<64, 256, 0, stream>>>(W3, WTh3, WTl3);

    // layer 1: x = tiled emb (gmask folds node id onto the 1024-row table)
    k_layer<<<NN / 128, 512, 0, stream>>>(emb, NPN - 1, WTh1, WTl1, b1,
                                          dinv, coff, cmeta, out);
    // layer 2: out -> x_mid
    k_layer<<<NN / 128, 512, 0, stream>>>(out, 0xFFFFFFFFu, WTh2, WTl2, b2,
                                          dinv, coff, cmeta, x_mid);
    // layer 3: x_mid -> out
    k_layer<<<NN / 128, 512, 0, stream>>>(x_mid, 0xFFFFFFFFu, WTh3, WTl3, b3,
                                          dinv, coff, cmeta, out);
}

// Round 5
// 1199.926 us; speedup vs baseline: 2.0958x; 1.0261x over previous
//
#include <hip/hip_runtime.h>

#define NPN   1024            // nodes per slice
#define NB    512             // batch (slices)
#define NE_S  2048            // edges per slice
#define DD    128             // feature dim
#define NN    (NB * NPN)      // 524288 total nodes
#define NE    (NB * NE_S)     // 1048576 total edges

typedef short s16x8 __attribute__((ext_vector_type(8)));
typedef float f32x4 __attribute__((ext_vector_type(4)));

static __device__ __forceinline__ unsigned short f2bf(float f) {
    unsigned u = __builtin_bit_cast(unsigned, f);
    unsigned r = (u + 0x7FFFu + ((u >> 16) & 1u)) >> 16;   // RNE
    return (unsigned short)r;
}
static __device__ __forceinline__ float bf2f(unsigned short h) {
    unsigned u = ((unsigned)h) << 16;
    return __builtin_bit_cast(float, u);
}

// ---------- CSR / degree precompute (layer-invariant) ----------

__global__ void k_count(const int* __restrict__ ei, int* __restrict__ deg) {
    int t = blockIdx.x * 256 + threadIdx.x;          // 0..NE-1
    int b = t >> 11, e = t & (NE_S - 1);
    int col = ei[b * (2 * NE_S) + NE_S + e];
    atomicAdd(&deg[b * NPN + col], 1);
}

__global__ void k_dinv(const int* __restrict__ deg, float* __restrict__ dinv) {
    int i = blockIdx.x * 256 + threadIdx.x;
    dinv[i] = rsqrtf((float)(deg[i] + 1));           // +1 self-loop
}

__global__ __launch_bounds__(1024) void k_scan(const int* __restrict__ deg,
                                               int* __restrict__ coff,
                                               int* __restrict__ cur) {
    __shared__ int s[NPN];
    int b = blockIdx.x, t = threadIdx.x;
    int v = deg[b * NPN + t];
    s[t] = v;
    __syncthreads();
    for (int off = 1; off < NPN; off <<= 1) {
        int add = (t >= off) ? s[t - off] : 0;
        __syncthreads();
        s[t] += add;
        __syncthreads();
    }
    coff[b * NPN + t] = b * NE_S + (s[t] - v);       // exclusive prefix, global offset
    cur[b * NPN + t] = 0;
}

// packed edge meta: .x = src_local | (dst_local<<16), .y = bitcast(norm)
__global__ void k_fill(const int* __restrict__ ei, const float* __restrict__ dinv,
                       const int* __restrict__ coff, int* __restrict__ cur,
                       int2* __restrict__ cmeta) {
    int t = blockIdx.x * 256 + threadIdx.x;
    int b = t >> 11, e = t & (NE_S - 1);
    int r = ei[b * (2 * NE_S) + e];
    int c = ei[b * (2 * NE_S) + NE_S + e];
    int gr = b * NPN + r, gc = b * NPN + c;
    int pos = coff[gc] + atomicAdd(&cur[gc], 1);
    float nw = dinv[gr] * dinv[gc];
    cmeta[pos] = make_int2(r | (c << 16), __builtin_bit_cast(int, nw));
}

// ---------- W pre-transpose + bf16 hi/lo split (per layer, tiny) ----------

__global__ __launch_bounds__(256) void k_wsplit(const float* __restrict__ W,
                                                short* __restrict__ WTh,
                                                short* __restrict__ WTl) {
    int idx = blockIdx.x * 256 + threadIdx.x;        // 0..16383
    int k = idx >> 7, n = idx & 127;
    float f = W[idx];
    unsigned short h = f2bf(f);
    unsigned short l = f2bf(f - bf2f(h));
    WTh[n * DD + k] = (short)h;
    WTl[n * DD + k] = (short)l;
}

// ---------- fused GCN layer: out = relu((A_hat x) @ W + b) ----------
// 512 thr / 8 waves / block; 64x128 output tile; 32 KiB LDS union
//   (4 blocks/CU, 32 waves/CU -> latency hiding + barrier overlap):
//   phase A: fp32 accumulator sAcc[64][128], de-interleaved cols.
//   phase B: bf16 hi half [0,16K) + lo half [16K,32K), XOR-swizzled.
// Gather: wave w owns rows w*8..+7 and their contiguous CSR edge range;
// meta broadcast via v_readlane (scalar control), 8 row-loads in flight,
// run-based accumulation (edges dst-sorted) -> LDS add per run.

__global__ __launch_bounds__(512, 8) void k_layer(const float* __restrict__ x,
                                                  unsigned gmask,
                                                  const short* __restrict__ WTh,
                                                  const short* __restrict__ WTl,
                                                  const float* __restrict__ bias,
                                                  const float* __restrict__ dinv,
                                                  const int* __restrict__ coff,
                                                  const int2* __restrict__ cmeta,
                                                  float* __restrict__ out) {
    __shared__ float sBuf[64 * DD];      // 32 KiB union
    float* sAcc = sBuf;
    char*  sH   = (char*)sBuf;           // after repack: hi bytes [0,16K)
    char*  sL   = (char*)sBuf + 16384;   // lo bytes [16K,32K)

    int t = threadIdx.x;
    int wave = t >> 6, lane = t & 63;
    // XCD-aware swizzle: 8192 blocks = 8 XCDs x 1024; 16 consecutive
    // blocks (one slice) land on one XCD -> slice rows L2-hit.
    int wb = (int)((blockIdx.x & 7) * 1024 + (blockIdx.x >> 3));
    int m0 = wb * 64;
    int sbase = (wb >> 4) << 10;         // slice base node

    int n  = lane & 15;
    int kq = lane >> 4;

    // wave's CSR range (scalarized -> uniform control flow)
    int r0g = m0 + wave * 8;
    int eBeg = __builtin_amdgcn_readfirstlane(coff[r0g]);
    int eEnd = __builtin_amdgcn_readfirstlane((r0g + 8 < NN) ? coff[r0g + 8] : NE);

    // ---- B fragments from global (L2-resident 64 KB, loaded once) ----
    const short* bhp = &WTh[(wave * 16 + n) * DD + kq * 8];
    const short* blp = &WTl[(wave * 16 + n) * DD + kq * 8];
    s16x8 bh[4], bl[4];
    #pragma unroll
    for (int ks = 0; ks < 4; ++ks) {
        bh[ks] = *(const s16x8*)(bhp + ks * 32);
        bl[ks] = *(const s16x8*)(blp + ks * 32);
    }

    // ---- self-loop init: rows wave*8..+7, lane covers features 2l,2l+1 ----
    {
        float2 sv[8]; float dvv[8];
        #pragma unroll
        for (int i = 0; i < 8; ++i) {
            int g = m0 + wave * 8 + i;
            dvv[i] = dinv[g];
            sv[i] = *(const float2*)&x[(size_t)((unsigned)g & gmask) * DD + lane * 2];
        }
        #pragma unroll
        for (int i = 0; i < 8; ++i) {
            int row = wave * 8 + i;
            float s = dvv[i] * dvv[i];
            sAcc[row * DD + lane]      = s * sv[i].x;
            sAcc[row * DD + 64 + lane] = s * sv[i].y;
        }
    }
    // no barrier needed: this wave only touches its own 8 rows below

    // ---- edge walk: run-based accumulation, 8 loads in flight ----
    float ax = 0.f, ay = 0.f;
    int curRow = -1;
    for (int c0 = eBeg; c0 < eEnd; c0 += 64) {
        int nC = eEnd - c0; nC = nC > 64 ? 64 : nC;
        // pad lanes: src10=0 (valid row, w=0), dst10=0xFFFF (run-breaker)
        int2 md = make_int2((int)0xFFFF0000u, 0);
        if (lane < nC) md = cmeta[c0 + lane];
        int nB = (nC + 7) & ~7;
        for (int b0 = 0; b0 < nB; b0 += 8) {
            float2 v[8]; int pj[8];
            #pragma unroll
            for (int j = 0; j < 8; ++j) {
                pj[j] = __builtin_amdgcn_readlane(md.x, b0 + j);
                int src = sbase + (pj[j] & 0xFFFF);
                v[j] = *(const float2*)&x[(size_t)((unsigned)src & gmask) * DD + lane * 2];
            }
            #pragma unroll
            for (int j = 0; j < 8; ++j) {
                int dst = sbase + (int)(((unsigned)pj[j]) >> 16);
                float w = __builtin_bit_cast(float, __builtin_amdgcn_readlane(md.y, b0 + j));
                if (dst != curRow) {
                    unsigned rl = (unsigned)(curRow - m0);
                    if (rl < 64u) {
                        atomicAdd(&sAcc[rl * DD + lane],      ax);
                        atomicAdd(&sAcc[rl * DD + 64 + lane], ay);
                    }
                    curRow = dst; ax = 0.f; ay = 0.f;
                }
                ax = fmaf(w, v[j].x, ax);
                ay = fmaf(w, v[j].y, ay);
            }
        }
    }
    {
        unsigned rl = (unsigned)(curRow - m0);
        if (rl < 64u) {
            atomicAdd(&sAcc[rl * DD + lane],      ax);
            atomicAdd(&sAcc[rl * DD + 64 + lane], ay);
        }
    }
    __syncthreads();

    // ---- in-place repack: fp32 -> bf16 hi/lo, XOR-swizzled ----
    float fe[8], fo[8];
    #pragma unroll
    for (int i = 0; i < 8; ++i) {
        int row = wave * 8 + i;
        fe[i] = sAcc[row * DD + lane];        // feature 2*lane
        fo[i] = sAcc[row * DD + 64 + lane];   // feature 2*lane+1
    }
    __syncthreads();
    #pragma unroll
    for (int i = 0; i < 8; ++i) {
        int row = wave * 8 + i;
        unsigned short hx = f2bf(fe[i]); unsigned short lx = f2bf(fe[i] - bf2f(hx));
        unsigned short hy = f2bf(fo[i]); unsigned short ly = f2bf(fo[i] - bf2f(hy));
        unsigned bo = ((unsigned)row * 256u + (unsigned)lane * 4u) ^ ((unsigned)(row & 7) << 4);
        *(unsigned*)(sH + bo) = ((unsigned)hy << 16) | hx;
        *(unsigned*)(sL + bo) = ((unsigned)ly << 16) | lx;
    }
    __syncthreads();

    // ---- MFMA phase: wave strip = rows 0..63, cols wave*16..+15 ----
    f32x4 acc[4];
    #pragma unroll
    for (int m = 0; m < 4; ++m) acc[m] = (f32x4){0.f, 0.f, 0.f, 0.f};

    #pragma unroll
    for (int ks = 0; ks < 4; ++ks) {
        #pragma unroll
        for (int m = 0; m < 4; ++m) {
            int row = m * 16 + n;
            unsigned bo = ((unsigned)row * 256u + (unsigned)(ks * 64 + kq * 16))
                          ^ ((unsigned)(row & 7) << 4);
            s16x8 ah = *(const s16x8*)(sH + bo);
            s16x8 al = *(const s16x8*)(sL + bo);
            acc[m] = __builtin_amdgcn_mfma_f32_16x16x32_bf16(ah, bh[ks], acc[m], 0, 0, 0);
            acc[m] = __builtin_amdgcn_mfma_f32_16x16x32_bf16(ah, bl[ks], acc[m], 0, 0, 0);
            acc[m] = __builtin_amdgcn_mfma_f32_16x16x32_bf16(al, bh[ks], acc[m], 0, 0, 0);
        }
    }

    // ---- epilogue: bias + relu; C/D layout col=lane&15, row=kq*4+reg ----
    int col = wave * 16 + n;
    float bv = bias[col];
    #pragma unroll
    for (int m = 0; m < 4; ++m) {
        #pragma unroll
        for (int r = 0; r < 4; ++r) {
            int row = m * 16 + kq * 4 + r;
            float vv = acc[m][r] + bv;
            out[(size_t)(m0 + row) * DD + col] = fmaxf(vv, 0.f);
        }
    }
}

// ---------- launch ----------

extern "C" void kernel_launch(void* const* d_in, const int* in_sizes, int n_in,
                              void* d_out, int out_size, void* d_ws, size_t ws_size,
                              hipStream_t stream) {
    const int*   ei  = (const int*)d_in[0];
    const float* emb = (const float*)d_in[1];
    const float* W1  = (const float*)d_in[2];
    const float* b1  = (const float*)d_in[3];
    const float* W2  = (const float*)d_in[4];
    const float* b2  = (const float*)d_in[5];
    const float* W3  = (const float*)d_in[6];
    const float* b3  = (const float*)d_in[7];
    float* out = (float*)d_out;

    float* x_mid = (float*)d_ws;                       // NN*DD floats (256 MiB)
    float* dinv  = x_mid + (size_t)NN * DD;
    int*   deg   = (int*)(dinv + NN);
    int*   coff  = deg + NN;
    int*   cur   = coff + NN;
    int2*  cmeta = (int2*)(cur + NN);                  // NE int2 (8 MiB)
    short* WTh1  = (short*)(cmeta + NE);
    short* WTl1  = WTh1 + DD * DD;
    short* WTh2  = WTl1 + DD * DD;
    short* WTl2  = WTh2 + DD * DD;
    short* WTh3  = WTl2 + DD * DD;
    short* WTl3  = WTh3 + DD * DD;

    hipMemsetAsync(deg, 0, NN * sizeof(int), stream);
    k_count<<<NE / 256, 256, 0, stream>>>(ei, deg);
    k_dinv<<<NN / 256, 256, 0, stream>>>(deg, dinv);
    k_scan<<<NB, NPN, 0, stream>>>(deg, coff, cur);
    k_fill<<<NE / 256, 256, 0, stream>>>(ei, dinv, coff, cur, cmeta);

    k_wsplit<<<64, 256, 0, stream>>>(W1, WTh1, WTl1);
    k_wsplit<<<64, 256, 0, stream>>>(W2, WTh2, WTl2);
    k_wsplit<<<64, 256, 0, stream>>>(W3, WTh3, WTl3);

    // layer 1: x = tiled emb (gmask folds node id onto the 1024-row table)
    k_layer<<<NN / 64, 512, 0, stream>>>(emb, NPN - 1, WTh1, WTl1, b1,
                                         dinv, coff, cmeta, out);
    // layer 2: out -> x_mid
    k_layer<<<NN / 64, 512, 0, stream>>>(out, 0xFFFFFFFFu, WTh2, WTl2, b2,
                                         dinv, coff, cmeta, x_mid);
    // layer 3: x_mid -> out
    k_layer<<<NN / 64, 512, 0, stream>>>(x_mid, 0xFFFFFFFFu, WTh3, WTl3, b3,
                                         dinv, coff, cmeta, out);
}